// Round 1
// baseline (12291.779 us; speedup 1.0000x reference)
//
#include <hip/hip_runtime.h>

#define N_USERS 100000
#define N_ITEMS 50000
#define N_NODES 150000
#define EMB 64
#define N_EDGES 4800000
#define N_LAYERS 3

// Number of float4 chunks per node embedding
#define CH (EMB / 4)              // 16
#define NODE_F4 (N_NODES * CH)    // 2,400,000 float4s

// init: x = ego (concat user/item), out = 0.25 * ego
__global__ __launch_bounds__(256) void init_kernel(
        const float4* __restrict__ user, const float4* __restrict__ item,
        float4* __restrict__ x, float4* __restrict__ out) {
    int i = blockIdx.x * blockDim.x + threadIdx.x;
    if (i >= NODE_F4) return;
    const int u4 = N_USERS * CH;
    float4 v = (i < u4) ? user[i] : item[i - u4];
    x[i] = v;
    float4 o;
    o.x = 0.25f * v.x; o.y = 0.25f * v.y; o.z = 0.25f * v.z; o.w = 0.25f * v.w;
    out[i] = o;
}

// scatter: y[row[e]] += val[e] * x[col[e]]   (16 threads per edge, float4 each)
__global__ __launch_bounds__(256) void scatter_kernel(
        const int* __restrict__ row, const int* __restrict__ col,
        const float* __restrict__ val,
        const float4* __restrict__ x, float* __restrict__ y) {
    int tid = blockIdx.x * blockDim.x + threadIdx.x;
    int e = tid >> 4;           // edge index
    if (e >= N_EDGES) return;
    int g = tid & 15;           // float4 chunk within EMB
    int r = row[e];
    int c = col[e];
    float v = val[e];
    float4 xv = x[c * CH + g];
    float* yp = y + ((size_t)r * EMB + g * 4);
    unsafeAtomicAdd(yp + 0, v * xv.x);
    unsafeAtomicAdd(yp + 1, v * xv.y);
    unsafeAtomicAdd(yp + 2, v * xv.z);
    unsafeAtomicAdd(yp + 3, v * xv.w);
}

// finalize: r = relu(y); y = r (in-place, becomes next x); out += 0.25*r
__global__ __launch_bounds__(256) void finalize_kernel(
        float4* __restrict__ y, float4* __restrict__ out) {
    int i = blockIdx.x * blockDim.x + threadIdx.x;
    if (i >= NODE_F4) return;
    float4 v = y[i];
    float4 r;
    r.x = fmaxf(v.x, 0.0f); r.y = fmaxf(v.y, 0.0f);
    r.z = fmaxf(v.z, 0.0f); r.w = fmaxf(v.w, 0.0f);
    y[i] = r;
    float4 o = out[i];
    o.x += 0.25f * r.x; o.y += 0.25f * r.y;
    o.z += 0.25f * r.z; o.w += 0.25f * r.w;
    out[i] = o;
}

extern "C" void kernel_launch(void* const* d_in, const int* in_sizes, int n_in,
                              void* d_out, int out_size, void* d_ws, size_t ws_size,
                              hipStream_t stream) {
    const float* user_emb = (const float*)d_in[0];
    const float* item_emb = (const float*)d_in[1];
    const float* adj_val  = (const float*)d_in[2];
    const int*   adj_row  = (const int*)d_in[3];
    const int*   adj_col  = (const int*)d_in[4];
    float* out = (float*)d_out;

    // workspace: two ping-pong node-embedding buffers (38.4 MB each)
    float* buf0 = (float*)d_ws;
    float* buf1 = buf0 + (size_t)N_NODES * EMB;

    const int nodeBlocks = (NODE_F4 + 255) / 256;           // 9375
    const int edgeBlocks = (N_EDGES * 16 + 255) / 256;      // 300000

    init_kernel<<<nodeBlocks, 256, 0, stream>>>(
        (const float4*)user_emb, (const float4*)item_emb,
        (float4*)buf0, (float4*)out);

    float* x = buf0;
    float* y = buf1;
    for (int l = 0; l < N_LAYERS; ++l) {
        hipMemsetAsync(y, 0, (size_t)N_NODES * EMB * sizeof(float), stream);
        scatter_kernel<<<edgeBlocks, 256, 0, stream>>>(
            adj_row, adj_col, adj_val, (const float4*)x, y);
        finalize_kernel<<<nodeBlocks, 256, 0, stream>>>(
            (float4*)y, (float4*)out);
        // swap: relu'd y becomes next x; old x becomes next y
        float* t = x; x = y; y = t;
    }
}

// Round 2
// 1520.959 us; speedup vs baseline: 8.0816x; 8.0816x over previous
//
#include <hip/hip_runtime.h>

#define N_USERS 100000
#define N_ITEMS 50000
#define N_NODES 150000
#define EMB 64
#define N_EDGES 4800000
#define N_LAYERS 3

#define CH (EMB / 4)              // 16 float4 per node
#define NODE_F4 (N_NODES * CH)    // 2,400,000

#define SCAN_BLOCKS ((N_NODES + 255) / 256)   // 586

// ---------------- init: buf0 = ego, out = 0.25*ego ----------------
__global__ __launch_bounds__(256) void init_kernel(
        const float4* __restrict__ user, const float4* __restrict__ item,
        float4* __restrict__ x, float4* __restrict__ out) {
    int i = blockIdx.x * blockDim.x + threadIdx.x;
    if (i >= NODE_F4) return;
    const int u4 = N_USERS * CH;
    float4 v = (i < u4) ? user[i] : item[i - u4];
    x[i] = v;
    float4 o;
    o.x = 0.25f * v.x; o.y = 0.25f * v.y; o.z = 0.25f * v.z; o.w = 0.25f * v.w;
    out[i] = o;
}

// ---------------- CSR build ----------------
__global__ __launch_bounds__(256) void hist_kernel(
        const int* __restrict__ row, int* __restrict__ counts) {
    int i = blockIdx.x * blockDim.x + threadIdx.x;
    if (i < N_EDGES) atomicAdd(&counts[row[i]], 1);
}

// per-block sums of counts (256 per block)
__global__ __launch_bounds__(256) void scan1_kernel(
        const int* __restrict__ counts, int* __restrict__ blockSums) {
    __shared__ int tmp[256];
    int i = blockIdx.x * 256 + threadIdx.x;
    int v = (i < N_NODES) ? counts[i] : 0;
    tmp[threadIdx.x] = v;
    __syncthreads();
    for (int off = 128; off > 0; off >>= 1) {
        if (threadIdx.x < off) tmp[threadIdx.x] += tmp[threadIdx.x + off];
        __syncthreads();
    }
    if (threadIdx.x == 0) blockSums[blockIdx.x] = tmp[0];
}

// exclusive scan of blockSums (SCAN_BLOCKS <= 1024) in one block
__global__ __launch_bounds__(1024) void scan2_kernel(
        int* __restrict__ blockSums, int* __restrict__ rowStart) {
    __shared__ int tmp[1024];
    int tid = threadIdx.x;
    int v = (tid < SCAN_BLOCKS) ? blockSums[tid] : 0;
    tmp[tid] = v;
    __syncthreads();
    for (int off = 1; off < 1024; off <<= 1) {
        int t = (tid >= off) ? tmp[tid - off] : 0;
        __syncthreads();
        tmp[tid] += t;
        __syncthreads();
    }
    if (tid < SCAN_BLOCKS) blockSums[tid] = tmp[tid] - v;  // exclusive
    if (tid == 0) rowStart[N_NODES] = N_EDGES;
}

// per-block exclusive scan + block offset -> rowStart, cursor
__global__ __launch_bounds__(256) void scan3_kernel(
        const int* __restrict__ counts, const int* __restrict__ blockSums,
        int* __restrict__ rowStart, int* __restrict__ cursor) {
    __shared__ int tmp[256];
    int i = blockIdx.x * 256 + threadIdx.x;
    int tid = threadIdx.x;
    int v = (i < N_NODES) ? counts[i] : 0;
    tmp[tid] = v;
    __syncthreads();
    for (int off = 1; off < 256; off <<= 1) {
        int t = (tid >= off) ? tmp[tid - off] : 0;
        __syncthreads();
        tmp[tid] += t;
        __syncthreads();
    }
    if (i < N_NODES) {
        int excl = tmp[tid] - v + blockSums[blockIdx.x];
        rowStart[i] = excl;
        cursor[i]   = excl;
    }
}

// bucket-scatter edges into row-sorted order (order within row irrelevant)
__global__ __launch_bounds__(256) void sortscatter_kernel(
        const int* __restrict__ row, const int* __restrict__ col,
        const float* __restrict__ val,
        int* __restrict__ cursor, int2* __restrict__ sEdge) {
    int i = blockIdx.x * blockDim.x + threadIdx.x;
    if (i >= N_EDGES) return;
    int r = row[i];
    int pos = atomicAdd(&cursor[r], 1);
    sEdge[pos] = make_int2(col[i], __float_as_int(val[i]));
}

// ---------------- gather SpMM: one wave per row, lane = feature ----------------
// y[r,lane] = relu(sum_e val*x[col,lane]); out[r,lane] += 0.25*relu
__global__ __launch_bounds__(256) void gather_kernel(
        const int* __restrict__ rowStart, const int2* __restrict__ sEdge,
        const float* __restrict__ x, float* __restrict__ y,
        float* __restrict__ out) {
    int wid  = threadIdx.x >> 6;
    int lane = threadIdx.x & 63;
    int r = blockIdx.x * 4 + wid;
    if (r >= N_NODES) return;
    int start = rowStart[r];
    int end   = rowStart[r + 1];
    float acc = 0.0f;
    for (int base = start; base < end; base += 64) {
        int idx = base + lane;
        int2 ed = make_int2(0, 0);
        if (idx < end) ed = sEdge[idx];      // coalesced 512B batch load
        int cnt = end - base;
        if (cnt > 64) cnt = 64;
        #pragma unroll 4
        for (int j = 0; j < cnt; ++j) {
            int   c = (int)__builtin_amdgcn_readlane((unsigned)ed.x, (unsigned)j);
            float v = __int_as_float((int)__builtin_amdgcn_readlane((unsigned)ed.y, (unsigned)j));
            acc = fmaf(v, x[(size_t)c * EMB + lane], acc);  // 256B coalesced gather
        }
    }
    float rl = fmaxf(acc, 0.0f);
    size_t o = (size_t)r * EMB + lane;
    y[o] = rl;
    out[o] += 0.25f * rl;
}

extern "C" void kernel_launch(void* const* d_in, const int* in_sizes, int n_in,
                              void* d_out, int out_size, void* d_ws, size_t ws_size,
                              hipStream_t stream) {
    const float* user_emb = (const float*)d_in[0];
    const float* item_emb = (const float*)d_in[1];
    const float* adj_val  = (const float*)d_in[2];
    const int*   adj_row  = (const int*)d_in[3];
    const int*   adj_col  = (const int*)d_in[4];
    float* out = (float*)d_out;

    // ---- workspace layout (all 16B aligned) ----
    char* p = (char*)d_ws;
    int*  counts    = (int*)p;                 p += ((size_t)N_NODES * 4 + 15) & ~15ull;
    int*  rowStart  = (int*)p;                 p += ((size_t)(N_NODES + 1) * 4 + 15) & ~15ull;
    int*  cursor    = (int*)p;                 p += ((size_t)N_NODES * 4 + 15) & ~15ull;
    int*  blockSums = (int*)p;                 p += (size_t)4096;
    int2* sEdge     = (int2*)p;                p += (size_t)N_EDGES * 8;
    float* buf0     = (float*)p;               p += (size_t)N_NODES * EMB * 4;
    float* buf1     = (float*)p;

    const int edgeBlocks = (N_EDGES + 255) / 256;   // 18750
    const int nodeBlocks = (NODE_F4 + 255) / 256;   // 9375
    const int rowBlocks  = (N_NODES + 3) / 4;       // 37500

    // init ego + out
    init_kernel<<<nodeBlocks, 256, 0, stream>>>(
        (const float4*)user_emb, (const float4*)item_emb,
        (float4*)buf0, (float4*)out);

    // CSR build
    hipMemsetAsync(counts, 0, (size_t)N_NODES * 4, stream);
    hist_kernel<<<edgeBlocks, 256, 0, stream>>>(adj_row, counts);
    scan1_kernel<<<SCAN_BLOCKS, 256, 0, stream>>>(counts, blockSums);
    scan2_kernel<<<1, 1024, 0, stream>>>(blockSums, rowStart);
    scan3_kernel<<<SCAN_BLOCKS, 256, 0, stream>>>(counts, blockSums, rowStart, cursor);
    sortscatter_kernel<<<edgeBlocks, 256, 0, stream>>>(
        adj_row, adj_col, adj_val, cursor, sEdge);

    // 3 gather layers (relu + out-accumulate fused)
    float* x = buf0;
    float* y = buf1;
    for (int l = 0; l < N_LAYERS; ++l) {
        gather_kernel<<<rowBlocks, 256, 0, stream>>>(rowStart, sEdge, x, y, out);
        float* t = x; x = y; y = t;
    }
}